// Round 4
// baseline (5783.504 us; speedup 1.0000x reference)
//
#include <hip/hip_runtime.h>
#include <cmath>

typedef unsigned long long u64;

#define N_ANCH   147456      // 128*128*9
#define N_PRE    3000
#define N_POST   300
#define NWORDS   47          // ceil(3000/64)
#define SEL_CAP  4096
#define BAND_ROWS 32
#define BAND_PX   (BAND_ROWS * 128)   // 4096

// ---------------- weight transposes ----------------
__global__ void rpn_prep_w(const float* __restrict__ wb, float* __restrict__ wt) {
    int g = blockIdx.x * 256 + threadIdx.x;          // < 512*1024*9
    if (g >= 512 * 9216) return;
    int oc  = g / 9216;
    int rem = g - oc * 9216;                          // c*9 + tap
    wt[(size_t)rem * 512 + oc] = wb[g];
}

__global__ void rpn_prep_wht(const float* __restrict__ wc, const float* __restrict__ wr,
                             float* __restrict__ wht) {
    int i = blockIdx.x * 256 + threadIdx.x;           // < 512*56
    if (i >= 512 * 56) return;
    int c = i / 56, k = i - c * 56;
    float v = 0.f;
    if (k < 18)       v = wc[k * 512 + c];
    else if (k < 54)  v = wr[(k - 18) * 512 + c];
    wht[i] = v;
}

// ---------------- 3x3 conv 1024->512 + bias + relu (fp64 accumulate) ----------------
// Block: 256 thr = (tx 0..7: 16px each) x (ty 0..31: 1 oc each). Grid (16 ocT, 32 rows).
// xs in LDS as f64, padded layout: phys(L) = L + 2*(L>>3); row stride 168 doubles.
#define CK 4
#define XROW 168
__global__ __launch_bounds__(256, 2) void rpn_conv3x3(
    const float* __restrict__ x, const float* __restrict__ wt,
    const float* __restrict__ bb, double* __restrict__ base, int band) {
    const int ocT = blockIdx.x;          // 0..15
    const int hl  = blockIdx.y;          // 0..31
    const int h   = band * BAND_ROWS + hl;
    const int tid = threadIdx.x;
    const int tx  = tid & 7;             // pixel group: px0 = tx*16
    const int ty  = tid >> 3;            // oc lane 0..31
    const int ocB = ocT * 32;
    __shared__ double xs[CK * 3 * XROW]; // 16,128 B

    // zero halo: Lidx 0..3 -> phys 0..3 ; Lidx 132..135 -> phys 164..167
    if (tid < CK * 3 * 8) {
        int row = tid >> 3, j = tid & 7;
        int ph = (j < 4) ? j : (160 + j);
        xs[row * XROW + ph] = 0.0;
    }

    double acc[16];
    #pragma unroll
    for (int p = 0; p < 16; ++p) acc[p] = 0.0;

    for (int c0 = 0; c0 < 1024; c0 += CK) {
        __syncthreads();
        // stage x: CK*3 rows * 128 cols = 384 float4, 256 threads -> 2 iters
        #pragma unroll
        for (int it = 0; it < 2; ++it) {
            int i = tid + it * 256;
            if (i < CK * 3 * 32) {
                int col4 = i & 31;
                int row  = (i >> 5) % 3;
                int cc   = i / 96;
                int hh = h - 1 + row;
                float4 v = make_float4(0.f, 0.f, 0.f, 0.f);
                if (hh >= 0 && hh < 128)
                    v = *(const float4*)&x[((size_t)(c0 + cc) * 128 + hh) * 128 + col4 * 4];
                int L = 4 + col4 * 4;                 // logical double index
                int ph = L + 2 * (L >> 3);
                double* dst = &xs[(cc * 3 + row) * XROW];
                // two aligned double2 writes (phys contiguous within 8-group)
                double2 d0; d0.x = (double)v.x; d0.y = (double)v.y;
                double2 d1; d1.x = (double)v.z; d1.y = (double)v.w;
                int ph2 = (L + 2) + 2 * ((L + 2) >> 3);
                *(double2*)&dst[ph]  = d0;
                *(double2*)&dst[ph2] = d1;
            }
        }
        __syncthreads();
        #pragma unroll
        for (int cc = 0; cc < CK; ++cc) {
            // prefetch this cc's 9 weights (f32, L2-resident, coalesced over ty)
            float wf[9];
            #pragma unroll
            for (int t = 0; t < 9; ++t)
                wf[t] = wt[((size_t)(c0 + cc) * 9 + t) * 512 + ocB + ty];
            #pragma unroll
            for (int kh = 0; kh < 3; ++kh) {
                const double* rowp = &xs[(cc * 3 + kh) * XROW + tx * 20];
                double dreg[20];
                // aligned double2 reads at phys offsets {2,4,6,10,12,14,16,20,22,24}
                *(double2*)&dreg[0]  = *(const double2*)&rowp[2];
                *(double2*)&dreg[2]  = *(const double2*)&rowp[4];
                *(double2*)&dreg[4]  = *(const double2*)&rowp[6];
                *(double2*)&dreg[6]  = *(const double2*)&rowp[10];
                *(double2*)&dreg[8]  = *(const double2*)&rowp[12];
                *(double2*)&dreg[10] = *(const double2*)&rowp[14];
                *(double2*)&dreg[12] = *(const double2*)&rowp[16];
                *(double2*)&dreg[14] = *(const double2*)&rowp[20];
                *(double2*)&dreg[16] = *(const double2*)&rowp[22];
                *(double2*)&dreg[18] = *(const double2*)&rowp[24];
                #pragma unroll
                for (int kw = 0; kw < 3; ++kw) {
                    double wd = (double)wf[kh * 3 + kw];
                    #pragma unroll
                    for (int p = 0; p < 16; ++p)
                        acc[p] = fma(dreg[p + kw + 1], wd, acc[p]);
                }
            }
        }
    }
    // epilogue: bias + relu, store 16 doubles
    {
        int oc = ocB + ty;
        double bv = (double)bb[oc];
        double* dst = &base[(size_t)oc * BAND_PX + hl * 128 + tx * 16];
        #pragma unroll
        for (int p = 0; p < 16; ++p) {
            double r = acc[p] + bv;
            dst[p] = (r > 0.0) ? r : 0.0;
        }
    }
}

// ---------------- heads: 1x1 convs + softmax + decode (all fp64), k-split ----------------
// Block 256 thr: (pxl 0..15) x (half 0..1) x (kq 0..7).  Grid: 256 blocks/band (16 px each).
__global__ __launch_bounds__(256, 2) void rpn_heads(
    const double* __restrict__ base, const float* __restrict__ wht,
    const float* __restrict__ bc, const float* __restrict__ br,
    double* __restrict__ boxes_d, float* __restrict__ sc32,
    unsigned* __restrict__ keys32, u64* __restrict__ ukey, int band) {
    __shared__ double sacc[256 * 28];   // 57,344 B
    __shared__ double sred[16 * 56];    //  7,168 B
    const int tid  = threadIdx.x;
    const int pxl  = tid & 15;
    const int half = (tid >> 4) & 1;
    const int kq   = tid >> 5;
    const int px0  = blockIdx.x * 16;
    double acc[28];
    #pragma unroll
    for (int q = 0; q < 28; ++q) acc[q] = 0.0;
    for (int i = 0; i < 64; ++i) {
        int c = kq * 64 + i;
        double bv = base[(size_t)c * BAND_PX + px0 + pxl];
        const float4* w4 = (const float4*)&wht[c * 56 + half * 28];
        #pragma unroll
        for (int qq = 0; qq < 7; ++qq) {
            float4 wv = w4[qq];
            acc[qq * 4 + 0] = fma(bv, (double)wv.x, acc[qq * 4 + 0]);
            acc[qq * 4 + 1] = fma(bv, (double)wv.y, acc[qq * 4 + 1]);
            acc[qq * 4 + 2] = fma(bv, (double)wv.z, acc[qq * 4 + 2]);
            acc[qq * 4 + 3] = fma(bv, (double)wv.w, acc[qq * 4 + 3]);
        }
    }
    #pragma unroll
    for (int q = 0; q < 28; ++q) sacc[tid * 28 + q] = acc[q];
    __syncthreads();
    for (int t = tid; t < 16 * 56; t += 256) {
        int px = t / 56, q = t - px * 56;
        int hf = q / 28, qq = q - hf * 28;
        double s = 0.0;
        #pragma unroll
        for (int k = 0; k < 8; ++k)
            s += sacc[(((unsigned)k << 5 | (unsigned)hf << 4 | (unsigned)px)) * 28 + qq];
        double bia = (q < 18) ? (double)bc[q] : ((q < 54) ? (double)br[q - 18] : 0.0);
        sred[px * 56 + q] = s + bia;
    }
    __syncthreads();
    if (tid < 144) {
        int pl = tid / 9, a = tid - pl * 9;
        int gpx = band * BAND_PX + px0 + pl;
        int wix = gpx & 127, hix = gpx >> 7;
        float Xf = (float)(wix * 16), Yf = (float)(hix * 16);
        int ri = a / 3, si = a - ri * 3;
        double rr  = (ri == 0) ? 0.5 : ((ri == 1) ? 1.0 : 2.0);
        double scl = (si == 0) ? 8.0 : ((si == 1) ? 16.0 : 32.0);
        double wA = 16.0 * scl * sqrt(1.0 / rr);
        double hA = 16.0 * scl * sqrt(rr);
        // anchors are float32 in the reference (np.asarray(ba, np.float32))
        float c0 = (float)(-0.5 * wA), c1 = (float)(-0.5 * hA);
        float c2 = (float)( 0.5 * wA), c3 = (float)( 0.5 * hA);
        float ax1 = Xf + c0, ay1 = Yf + c1, ax2 = Xf + c2, ay2 = Yf + c3;
        float awf = ax2 - ax1, ahf = ay2 - ay1;
        float acxf = ax1 + 0.5f * awf, acyf = ay1 + 0.5f * ahf;
        double aw = (double)awf, ah = (double)ahf;
        double acx = (double)acxf, acy = (double)acyf;
        double l0 = sred[pl * 56 + 2 * a], l1 = sred[pl * 56 + 2 * a + 1];
        double dx = sred[pl * 56 + 18 + 4 * a + 0], dy = sred[pl * 56 + 18 + 4 * a + 1];
        double dw = sred[pl * 56 + 18 + 4 * a + 2], dh = sred[pl * 56 + 18 + 4 * a + 3];
        double cx = dx * aw + acx, cy = dy * ah + acy;
        double bw = exp(dw) * aw, bh = exp(dh) * ah;
        double x1 = cx - 0.5 * bw, y1 = cy - 0.5 * bh;
        double x2 = cx + 0.5 * bw, y2 = cy + 0.5 * bh;
        x1 = fmin(fmax(x1, 0.0), 2048.0);
        y1 = fmin(fmax(y1, 0.0), 2048.0);
        x2 = fmin(fmax(x2, 0.0), 2048.0);
        y2 = fmin(fmax(y2, 0.0), 2048.0);
        bool valid = (x2 - x1 >= 16.0) && (y2 - y1 >= 16.0);
        double m = fmax(l0, l1);
        double e0 = exp(l0 - m), e1 = exp(l1 - m);
        double fg = e1 / (e0 + e1);
        double msk = valid ? fg : -INFINITY;
        int aidx = gpx * 9 + a;
        double* bd = &boxes_d[(size_t)aidx * 4];
        bd[0] = x1; bd[1] = y1; bd[2] = x2; bd[3] = y2;
        float s32 = (float)msk;
        sc32[aidx] = s32;
        unsigned kb = __float_as_uint(s32);
        kb = (kb & 0x80000000u) ? ~kb : (kb | 0x80000000u);
        keys32[aidx] = kb;
        long long ll = __double_as_longlong(msk);
        u64 u = (ll < 0) ? ~(u64)ll : ((u64)ll | 0x8000000000000000ull);
        ukey[aidx] = (u & 0xFFFFFFFFFFFC0000ull) | (u64)(0x3FFFFu - (unsigned)aidx);
    }
}

// ---------------- top-k: two-level radix select on fp32 key ----------------
__global__ void rpn_hist1(const unsigned* __restrict__ keys, unsigned* __restrict__ hist) {
    int i = blockIdx.x * 256 + threadIdx.x;
    if (i < N_ANCH) atomicAdd(&hist[keys[i] >> 16], 1u);
}

__global__ void rpn_select1(const unsigned* __restrict__ hist, unsigned* __restrict__ meta) {
    __shared__ unsigned seg[256];
    __shared__ unsigned suf[257];
    int t = threadIdx.x;
    unsigned s = 0;
    for (int j = 0; j < 256; ++j) s += hist[t * 256 + j];
    seg[t] = s;
    __syncthreads();
    if (t == 0) {
        unsigned run = 0; suf[256] = 0;
        for (int q = 255; q >= 0; --q) { run += seg[q]; suf[q] = run; }
    }
    __syncthreads();
    if (suf[t + 1] < N_PRE && suf[t] >= N_PRE) {
        unsigned cum = suf[t + 1];
        for (int b = t * 256 + 255; b >= t * 256; --b) {
            unsigned prev = cum;
            cum += hist[b];
            if (cum >= N_PRE) { meta[0] = (unsigned)b; meta[1] = prev; break; }
        }
    }
}

__global__ void rpn_hist2(const unsigned* __restrict__ keys, const unsigned* __restrict__ meta,
                          unsigned* __restrict__ hist2) {
    int i = blockIdx.x * 256 + threadIdx.x;
    if (i >= N_ANCH) return;
    unsigned B = meta[0];
    unsigned k = keys[i];
    if ((k >> 16) == B) atomicAdd(&hist2[k & 0xFFFFu], 1u);
}

__global__ void rpn_select2(const unsigned* __restrict__ hist2, unsigned* __restrict__ meta) {
    __shared__ unsigned seg[256];
    __shared__ unsigned suf[257];
    int t = threadIdx.x;
    unsigned s = 0;
    for (int j = 0; j < 256; ++j) s += hist2[t * 256 + j];
    seg[t] = s;
    __syncthreads();
    if (t == 0) {
        unsigned run = 0; suf[256] = 0;
        for (int q = 255; q >= 0; --q) { run += seg[q]; suf[q] = run; }
    }
    __syncthreads();
    unsigned need = N_PRE - meta[1];          // >= 1 by construction
    if (suf[t + 1] < need && suf[t] >= need) {
        unsigned cum = suf[t + 1];
        for (int b = t * 256 + 255; b >= t * 256; --b) {
            cum += hist2[b];
            if (cum >= need) { meta[3] = (meta[0] << 16) | (unsigned)b; break; }
        }
    }
}

__global__ void rpn_compact(const unsigned* __restrict__ keys, unsigned* meta,
                            const u64* __restrict__ ukey, u64* __restrict__ sel) {
    int i = blockIdx.x * 256 + threadIdx.x;
    if (i >= N_ANCH) return;
    unsigned thr = meta[3];
    if (keys[i] >= thr) {
        unsigned pos = atomicAdd(&meta[4], 1u);
        if (pos < SEL_CAP) sel[pos] = ukey[i];
    }
}

__global__ __launch_bounds__(512) void rpn_sort(
    const u64* __restrict__ sel, const unsigned* __restrict__ meta,
    const double* __restrict__ boxes_d, const float* __restrict__ sc32,
    float* __restrict__ out, double* __restrict__ bsel, unsigned* __restrict__ vsel) {
    __shared__ u64 ss[SEL_CAP];
    int tid = threadIdx.x;
    int M = (int)meta[4]; if (M > SEL_CAP) M = SEL_CAP;
    for (int i = tid; i < SEL_CAP; i += 512) ss[i] = (i < M) ? sel[i] : 0ULL;
    __syncthreads();
    for (int k = 2; k <= SEL_CAP; k <<= 1) {
        for (int j = k >> 1; j > 0; j >>= 1) {
            for (int i = tid; i < SEL_CAP; i += 512) {
                int l = i ^ j;
                if (l > i) {
                    u64 a = ss[i], b = ss[l];
                    bool desc = (i & k) == 0;
                    if ((a < b) == desc) { ss[i] = b; ss[l] = a; }
                }
            }
            __syncthreads();
        }
    }
    for (int r = tid; r < N_PRE; r += 512) {
        u64 key = ss[r];
        unsigned idx = 0x3FFFFu - (unsigned)(key & 0x3FFFFull);
        out[N_POST * 4 + r] = sc32[idx];
        const double* bd = &boxes_d[(size_t)idx * 4];
        double* dst = &bsel[(size_t)r * 4];
        dst[0] = bd[0]; dst[1] = bd[1]; dst[2] = bd[2]; dst[3] = bd[3];
        vsel[r] = (key >> 63) ? 1u : 0u;      // sign bit set <=> score >= 0 <=> valid
    }
}

// ---------------- NMS (fp64 IoU) ----------------
__global__ void rpn_nms_mask(const double* __restrict__ bsel, u64* __restrict__ mask) {
    int t = blockIdx.x * 256 + threadIdx.x;
    if (t >= N_PRE * NWORDS) return;
    int i = t / NWORDS, w = t - i * NWORDS;
    const double* bi = &bsel[(size_t)i * 4];
    double bix1 = bi[0], biy1 = bi[1], bix2 = bi[2], biy2 = bi[3];
    double ai = (bix2 - bix1 + 1.0) * (biy2 - biy1 + 1.0);
    u64 bits = 0ULL;
    int j0 = w * 64;
    for (int jj = 0; jj < 64; ++jj) {
        int j = j0 + jj;
        if (j >= N_PRE || j == i) continue;
        const double* bj = &bsel[(size_t)j * 4];
        double aj = (bj[2] - bj[0] + 1.0) * (bj[3] - bj[1] + 1.0);
        double xx1 = fmax(bix1, bj[0]), yy1 = fmax(biy1, bj[1]);
        double xx2 = fmin(bix2, bj[2]), yy2 = fmin(biy2, bj[3]);
        double iw = fmax(xx2 - xx1 + 1.0, 0.0), ih = fmax(yy2 - yy1 + 1.0, 0.0);
        double inter = iw * ih;
        double iou = inter / (ai + aj - inter);
        if (iou > 0.5) bits |= 1ULL << jj;
    }
    mask[(size_t)i * NWORDS + w] = bits;
}

__global__ __launch_bounds__(64) void rpn_nms_scan(
    const u64* __restrict__ mask, const unsigned* __restrict__ vsel,
    unsigned* __restrict__ keep, unsigned* __restrict__ rank) {
    int lane = threadIdx.x;
    u64 remv = 0ULL;
    int kc = 0;
    u64 pre[8];
    #pragma unroll
    for (int q = 0; q < 8; ++q)
        pre[q] = (lane < NWORDS) ? mask[(size_t)q * NWORDS + lane] : 0ULL;
    for (int i0 = 0; i0 < N_PRE; i0 += 8) {
        u64 nxt[8];
        #pragma unroll
        for (int q = 0; q < 8; ++q) {
            int r = i0 + 8 + q;
            nxt[q] = (r < N_PRE && lane < NWORDS) ? mask[(size_t)r * NWORDS + lane] : 0ULL;
        }
        #pragma unroll
        for (int q = 0; q < 8; ++q) {
            int i = i0 + q;
            int word = i >> 6, bit = i & 63;
            u64 rw = __shfl(remv, word);
            bool sup = (rw >> bit) & 1ULL;
            bool kp = (vsel[i] != 0u) && !sup;
            if (kp) remv |= pre[q];
            if (lane == 0) { keep[i] = kp ? 1u : 0u; rank[i] = (unsigned)kc; }
            kc += kp ? 1 : 0;
        }
        #pragma unroll
        for (int q = 0; q < 8; ++q) pre[q] = nxt[q];
    }
}

__global__ void rpn_finalize(const unsigned* __restrict__ keep, const unsigned* __restrict__ rank,
                             const double* __restrict__ bsel, float* __restrict__ out) {
    int i = blockIdx.x * 256 + threadIdx.x;
    if (i < N_PRE && keep[i] && rank[i] < N_POST) {
        const double* b = &bsel[(size_t)i * 4];
        float4 v = make_float4((float)b[0], (float)b[1], (float)b[2], (float)b[3]);
        ((float4*)out)[rank[i]] = v;
    }
}

// ---------------- launch ----------------
extern "C" void kernel_launch(void* const* d_in, const int* in_sizes, int n_in,
                              void* d_out, int out_size, void* d_ws, size_t ws_size,
                              hipStream_t stream) {
    const float* x   = (const float*)d_in[0];
    const float* wb  = (const float*)d_in[1];
    const float* bb  = (const float*)d_in[2];
    const float* wc  = (const float*)d_in[3];
    const float* bc  = (const float*)d_in[4];
    const float* wr  = (const float*)d_in[5];
    const float* br  = (const float*)d_in[6];
    float* out = (float*)d_out;

    char* ws = (char*)d_ws;
    // Compact layout, total 44,661,504 bytes (< 57 MB proven-safe footprint).
    float*    wt      = (float*)(ws);                        //  0         18,874,368
    double*   baseB   = (double*)(ws + 18874368);            //            16,777,216 (one 32-row band, fp64)
    float*    wht     = (float*)(ws + 35651584);             //               114,688
    double*   boxes_d = (double*)(ws + 35766272);            //             4,718,592
    float*    sc32    = (float*)(ws + 40484864);             //               589,824
    unsigned* keys32  = (unsigned*)(ws + 41074688);          //               589,824
    u64*      ukey    = (u64*)(ws + 41664512);               //             1,179,648
    unsigned* hist1   = (unsigned*)(ws + 42844160);          //               262,144
    unsigned* hist2   = (unsigned*)(ws + 43106304);          //               262,144
    unsigned* meta    = (unsigned*)(ws + 43368448);          //                   256
    u64*      sel     = (u64*)(ws + 43368704);               //                32,768
    double*   bsel    = (double*)(ws + 43401472);            //                96,000
    unsigned* vsel    = (unsigned*)(ws + 43497472);          //                12,032
    u64*      mask    = (u64*)(ws + 43509504);               //             1,128,000
    unsigned* keep    = (unsigned*)(ws + 44637504);          //                12,000
    unsigned* rank    = (unsigned*)(ws + 44649504);          //                12,000

    hipMemsetAsync(hist1, 0, 262144 * 2 + 256, stream);      // hist1+hist2+meta (contiguous)
    hipMemsetAsync(d_out, 0, N_POST * 4 * sizeof(float), stream);

    rpn_prep_w  <<<18432, 256, 0, stream>>>(wb, wt);
    rpn_prep_wht<<<112,   256, 0, stream>>>(wc, wr, wht);
    for (int band = 0; band < 4; ++band) {
        rpn_conv3x3 <<<dim3(16, BAND_ROWS), 256, 0, stream>>>(x, wt, bb, baseB, band);
        rpn_heads   <<<BAND_PX / 16, 256, 0, stream>>>(baseB, wht, bc, br,
                                                       boxes_d, sc32, keys32, ukey, band);
    }
    rpn_hist1   <<<576, 256, 0, stream>>>(keys32, hist1);
    rpn_select1 <<<1, 256, 0, stream>>>(hist1, meta);
    rpn_hist2   <<<576, 256, 0, stream>>>(keys32, meta, hist2);
    rpn_select2 <<<1, 256, 0, stream>>>(hist2, meta);
    rpn_compact <<<576, 256, 0, stream>>>(keys32, meta, ukey, sel);
    rpn_sort    <<<1, 512, 0, stream>>>(sel, meta, boxes_d, sc32, out, bsel, vsel);
    rpn_nms_mask<<<(N_PRE * NWORDS + 255) / 256, 256, 0, stream>>>(bsel, mask);
    rpn_nms_scan<<<1, 64, 0, stream>>>(mask, vsel, keep, rank);
    rpn_finalize<<<12, 256, 0, stream>>>(keep, rank, bsel, out);
}

// Round 5
// 4422.482 us; speedup vs baseline: 1.3078x; 1.3078x over previous
//
#include <hip/hip_runtime.h>
#include <cmath>

typedef unsigned long long u64;

#define N_ANCH   147456      // 128*128*9
#define N_PRE    3000
#define N_POST   300
#define NWORDS   47          // ceil(3000/64)
#define SEL_CAP  4096

// ---------------- weight transposes ----------------
__global__ void rpn_prep_w(const float* __restrict__ wb, float* __restrict__ wt) {
    int g = blockIdx.x * 256 + threadIdx.x;          // < 512*1024*9
    if (g >= 512 * 9216) return;
    int oc  = g / 9216;
    int rem = g - oc * 9216;                          // c*9 + tap
    wt[(size_t)rem * 512 + oc] = wb[g];
}

__global__ void rpn_prep_wht(const float* __restrict__ wc, const float* __restrict__ wr,
                             float* __restrict__ wht) {
    int i = blockIdx.x * 256 + threadIdx.x;           // < 512*56
    if (i >= 512 * 56) return;
    int c = i / 56, k = i - c * 56;
    float v = 0.f;
    if (k < 18)       v = wc[k * 512 + c];
    else if (k < 54)  v = wr[(k - 18) * 512 + c];
    wht[i] = v;
}

// ---------------- fused 3x3 conv (f64 acc) + relu + 1x1 heads -> logits ----------------
// Block: 256 thr = (tx 0..15: 8 px) x (ty 0..15: 4 oc). Grid (128 rows, 8 ocT).
// Block covers 1 row x 64 oc x full K; epilogue folds heads into logits[px][56] via
// shfl+LDS reduce and global f64 atomicAdd (8 ocT contenders per cell).
#define CKF 8
#define XR  136            // row stride in floats; payload cols at idx 4..131
__global__ __launch_bounds__(256, 3) void rpn_conv_fused(
    const float* __restrict__ x, const float* __restrict__ wt,
    const float* __restrict__ bb, const float* __restrict__ wht_,
    double* __restrict__ logits) {
    const int row = blockIdx.x;          // 0..127
    const int ocT = blockIdx.y;          // 0..7
    const int tid = threadIdx.x;
    const int tx  = tid & 15;            // px group: px = tx*8 .. tx*8+7
    const int ty  = tid >> 4;            // oc group: oc = ocT*64 + ty*4 ..+3
    const int ocB = ocT * 64;
    __shared__ __attribute__((aligned(16))) float xs[CKF][3][XR];   // 13,056 B
    __shared__ __attribute__((aligned(16))) float ws[CKF][9][64];   // 18,432 B
    __shared__ double red[4][16][8][4];                             // 16,384 B

    // zero halo slots once: idx 0..3 (col -1 pad) and 132..135 (col 128 pad)
    if (tid < CKF * 3) {
        int cc = tid / 3, r3 = tid - cc * 3;
        #pragma unroll
        for (int j = 0; j < 4; ++j) { xs[cc][r3][j] = 0.f; xs[cc][r3][132 + j] = 0.f; }
    }

    double acc[8][4];
    #pragma unroll
    for (int p = 0; p < 8; ++p)
        #pragma unroll
        for (int o = 0; o < 4; ++o) acc[p][o] = 0.0;

    for (int c0 = 0; c0 < 1024; c0 += CKF) {
        __syncthreads();
        // stage x: CKF*3 rows * 32 float4 = 768 float4, 256 thr -> 3 each
        #pragma unroll
        for (int it = 0; it < 3; ++it) {
            int i = tid + it * 256;
            int col4 = i & 31;
            int r3   = (i >> 5) % 3;
            int cc   = i / 96;
            int hh = row - 1 + r3;
            float4 v = make_float4(0.f, 0.f, 0.f, 0.f);
            if (hh >= 0 && hh < 128)
                v = *(const float4*)&x[((size_t)(c0 + cc) * 128 + hh) * 128 + col4 * 4];
            *(float4*)&xs[cc][r3][4 + col4 * 4] = v;     // 16B-aligned
        }
        // stage w: CKF*9*64 = 4608 floats, 18 per thread, coalesced over ocl
        #pragma unroll
        for (int it = 0; it < 18; ++it) {
            int i = tid + it * 256;
            int ocl = i & 63;
            int t   = (i >> 6) % 9;
            int cc  = i / 576;
            ws[cc][t][ocl] = wt[((size_t)(c0 + cc) * 9 + t) * 512 + ocB + ocl];
        }
        __syncthreads();
        #pragma unroll
        for (int cc = 0; cc < CKF; ++cc) {
            #pragma unroll
            for (int kh = 0; kh < 3; ++kh) {
                float a[16];
                *(float4*)&a[0]  = *(const float4*)&xs[cc][kh][tx * 8];
                *(float4*)&a[4]  = *(const float4*)&xs[cc][kh][tx * 8 + 4];
                *(float4*)&a[8]  = *(const float4*)&xs[cc][kh][tx * 8 + 8];
                *(float4*)&a[12] = *(const float4*)&xs[cc][kh][tx * 8 + 12];
                double ad[12];                      // cols tx*8-1 .. tx*8+10
                #pragma unroll
                for (int q = 0; q < 12; ++q) ad[q] = (double)a[q + 3];
                #pragma unroll
                for (int kw = 0; kw < 3; ++kw) {
                    float4 wv = *(const float4*)&ws[cc][kh * 3 + kw][ty * 4];
                    double w0 = (double)wv.x, w1 = (double)wv.y;
                    double w2 = (double)wv.z, w3 = (double)wv.w;
                    #pragma unroll
                    for (int p = 0; p < 8; ++p) {
                        acc[p][0] = fma(ad[p + kw], w0, acc[p][0]);
                        acc[p][1] = fma(ad[p + kw], w1, acc[p][1]);
                        acc[p][2] = fma(ad[p + kw], w2, acc[p][2]);
                        acc[p][3] = fma(ad[p + kw], w3, acc[p][3]);
                    }
                }
            }
        }
    }

    // ---- epilogue: bias + relu, fold heads, reduce, atomic add ----
    double r_[8][4];
    {
        int oc0 = ocB + ty * 4;
        #pragma unroll
        for (int o = 0; o < 4; ++o) {
            double bv = (double)bb[oc0 + o];
            #pragma unroll
            for (int p = 0; p < 8; ++p) {
                double r = acc[p][o] + bv;
                r_[p][o] = (r > 0.0) ? r : 0.0;
            }
        }
    }
    const int wave = tid >> 6;
    const int lane = tid & 63;
    const int oc0  = ocB + ty * 4;
    for (int qc = 0; qc < 14; ++qc) {
        double wq[4][4];
        #pragma unroll
        for (int o = 0; o < 4; ++o)
            #pragma unroll
            for (int qq = 0; qq < 4; ++qq)
                wq[o][qq] = (double)wht_[(size_t)(oc0 + o) * 56 + qc * 4 + qq];
        #pragma unroll
        for (int p = 0; p < 8; ++p) {
            #pragma unroll
            for (int qq = 0; qq < 4; ++qq) {
                double s = r_[p][0] * wq[0][qq];
                s = fma(r_[p][1], wq[1][qq], s);
                s = fma(r_[p][2], wq[2][qq], s);
                s = fma(r_[p][3], wq[3][qq], s);
                s += __shfl_xor(s, 16);          // sum ty pairs
                s += __shfl_xor(s, 32);          // -> sum over wave's 4 ty (16 oc)
                if (lane < 16) red[wave][lane][p][qq] = s;
            }
        }
        __syncthreads();
        // 16tx*8p*4qq = 512 cells, 2 per thread: cross-wave sum + global atomic
        #pragma unroll
        for (int k = 0; k < 2; ++k) {
            int cell = tid * 2 + k;
            int txc = cell >> 5, p = (cell >> 2) & 7, qq = cell & 3;
            double s4 = red[0][txc][p][qq] + red[1][txc][p][qq]
                      + red[2][txc][p][qq] + red[3][txc][p][qq];
            atomicAdd(&logits[(size_t)(row * 128 + txc * 8 + p) * 56 + qc * 4 + qq], s4);
        }
        __syncthreads();
    }
}

// ---------------- decode: softmax + anchors + clip + keys (all fp64) ----------------
__global__ void rpn_decode(
    const double* __restrict__ logits, const float* __restrict__ bc,
    const float* __restrict__ br, double* __restrict__ boxes_d,
    float* __restrict__ sc32, unsigned* __restrict__ keys32, u64* __restrict__ ukey) {
    int aidx = blockIdx.x * 256 + threadIdx.x;
    if (aidx >= N_ANCH) return;
    int px = aidx / 9, a = aidx - px * 9;
    int wix = px & 127, hix = px >> 7;
    float Xf = (float)(wix * 16), Yf = (float)(hix * 16);
    int ri = a / 3, si = a - ri * 3;
    double rr  = (ri == 0) ? 0.5 : ((ri == 1) ? 1.0 : 2.0);
    double scl = (si == 0) ? 8.0 : ((si == 1) ? 16.0 : 32.0);
    double wA = 16.0 * scl * sqrt(1.0 / rr);
    double hA = 16.0 * scl * sqrt(rr);
    // anchors are float32 in the reference (np.asarray(ba, np.float32))
    float c0 = (float)(-0.5 * wA), c1 = (float)(-0.5 * hA);
    float c2 = (float)( 0.5 * wA), c3 = (float)( 0.5 * hA);
    float ax1 = Xf + c0, ay1 = Yf + c1, ax2 = Xf + c2, ay2 = Yf + c3;
    float awf = ax2 - ax1, ahf = ay2 - ay1;
    float acxf = ax1 + 0.5f * awf, acyf = ay1 + 0.5f * ahf;
    double aw = (double)awf, ah = (double)ahf;
    double acx = (double)acxf, acy = (double)acyf;
    const double* L = &logits[(size_t)px * 56];
    double l0 = L[2 * a]     + (double)bc[2 * a];
    double l1 = L[2 * a + 1] + (double)bc[2 * a + 1];
    double dx = L[18 + 4 * a + 0] + (double)br[4 * a + 0];
    double dy = L[18 + 4 * a + 1] + (double)br[4 * a + 1];
    double dw = L[18 + 4 * a + 2] + (double)br[4 * a + 2];
    double dh = L[18 + 4 * a + 3] + (double)br[4 * a + 3];
    double cx = dx * aw + acx, cy = dy * ah + acy;
    double bw = exp(dw) * aw, bh = exp(dh) * ah;
    double x1 = cx - 0.5 * bw, y1 = cy - 0.5 * bh;
    double x2 = cx + 0.5 * bw, y2 = cy + 0.5 * bh;
    x1 = fmin(fmax(x1, 0.0), 2048.0);
    y1 = fmin(fmax(y1, 0.0), 2048.0);
    x2 = fmin(fmax(x2, 0.0), 2048.0);
    y2 = fmin(fmax(y2, 0.0), 2048.0);
    bool valid = (x2 - x1 >= 16.0) && (y2 - y1 >= 16.0);
    double m = fmax(l0, l1);
    double e0 = exp(l0 - m), e1 = exp(l1 - m);
    double fg = e1 / (e0 + e1);
    double msk = valid ? fg : -INFINITY;
    double* bd = &boxes_d[(size_t)aidx * 4];
    bd[0] = x1; bd[1] = y1; bd[2] = x2; bd[3] = y2;
    float s32 = (float)msk;
    sc32[aidx] = s32;
    unsigned kb = __float_as_uint(s32);
    kb = (kb & 0x80000000u) ? ~kb : (kb | 0x80000000u);
    keys32[aidx] = kb;
    long long ll = __double_as_longlong(msk);
    u64 u = (ll < 0) ? ~(u64)ll : ((u64)ll | 0x8000000000000000ull);
    ukey[aidx] = (u & 0xFFFFFFFFFFFC0000ull) | (u64)(0x3FFFFu - (unsigned)aidx);
}

// ---------------- top-k: two-level radix select on fp32 key ----------------
__global__ void rpn_hist1(const unsigned* __restrict__ keys, unsigned* __restrict__ hist) {
    int i = blockIdx.x * 256 + threadIdx.x;
    if (i < N_ANCH) atomicAdd(&hist[keys[i] >> 16], 1u);
}

__global__ void rpn_select1(const unsigned* __restrict__ hist, unsigned* __restrict__ meta) {
    __shared__ unsigned seg[256];
    __shared__ unsigned suf[257];
    int t = threadIdx.x;
    unsigned s = 0;
    for (int j = 0; j < 256; ++j) s += hist[t * 256 + j];
    seg[t] = s;
    __syncthreads();
    if (t == 0) {
        unsigned run = 0; suf[256] = 0;
        for (int q = 255; q >= 0; --q) { run += seg[q]; suf[q] = run; }
    }
    __syncthreads();
    if (suf[t + 1] < N_PRE && suf[t] >= N_PRE) {
        unsigned cum = suf[t + 1];
        for (int b = t * 256 + 255; b >= t * 256; --b) {
            unsigned prev = cum;
            cum += hist[b];
            if (cum >= N_PRE) { meta[0] = (unsigned)b; meta[1] = prev; break; }
        }
    }
}

__global__ void rpn_hist2(const unsigned* __restrict__ keys, const unsigned* __restrict__ meta,
                          unsigned* __restrict__ hist2) {
    int i = blockIdx.x * 256 + threadIdx.x;
    if (i >= N_ANCH) return;
    unsigned B = meta[0];
    unsigned k = keys[i];
    if ((k >> 16) == B) atomicAdd(&hist2[k & 0xFFFFu], 1u);
}

__global__ void rpn_select2(const unsigned* __restrict__ hist2, unsigned* __restrict__ meta) {
    __shared__ unsigned seg[256];
    __shared__ unsigned suf[257];
    int t = threadIdx.x;
    unsigned s = 0;
    for (int j = 0; j < 256; ++j) s += hist2[t * 256 + j];
    seg[t] = s;
    __syncthreads();
    if (t == 0) {
        unsigned run = 0; suf[256] = 0;
        for (int q = 255; q >= 0; --q) { run += seg[q]; suf[q] = run; }
    }
    __syncthreads();
    unsigned need = N_PRE - meta[1];          // >= 1 by construction
    if (suf[t + 1] < need && suf[t] >= need) {
        unsigned cum = suf[t + 1];
        for (int b = t * 256 + 255; b >= t * 256; --b) {
            cum += hist2[b];
            if (cum >= need) { meta[3] = (meta[0] << 16) | (unsigned)b; break; }
        }
    }
}

__global__ void rpn_compact(const unsigned* __restrict__ keys, unsigned* meta,
                            const u64* __restrict__ ukey, u64* __restrict__ sel) {
    int i = blockIdx.x * 256 + threadIdx.x;
    if (i >= N_ANCH) return;
    unsigned thr = meta[3];
    if (keys[i] >= thr) {
        unsigned pos = atomicAdd(&meta[4], 1u);
        if (pos < SEL_CAP) sel[pos] = ukey[i];
    }
}

__global__ __launch_bounds__(512) void rpn_sort(
    const u64* __restrict__ sel, const unsigned* __restrict__ meta,
    const double* __restrict__ boxes_d, const float* __restrict__ sc32,
    float* __restrict__ out, double* __restrict__ bsel, unsigned* __restrict__ vsel) {
    __shared__ u64 ss[SEL_CAP];
    int tid = threadIdx.x;
    int M = (int)meta[4]; if (M > SEL_CAP) M = SEL_CAP;
    for (int i = tid; i < SEL_CAP; i += 512) ss[i] = (i < M) ? sel[i] : 0ULL;
    __syncthreads();
    for (int k = 2; k <= SEL_CAP; k <<= 1) {
        for (int j = k >> 1; j > 0; j >>= 1) {
            for (int i = tid; i < SEL_CAP; i += 512) {
                int l = i ^ j;
                if (l > i) {
                    u64 a = ss[i], b = ss[l];
                    bool desc = (i & k) == 0;
                    if ((a < b) == desc) { ss[i] = b; ss[l] = a; }
                }
            }
            __syncthreads();
        }
    }
    for (int r = tid; r < N_PRE; r += 512) {
        u64 key = ss[r];
        unsigned idx = 0x3FFFFu - (unsigned)(key & 0x3FFFFull);
        out[N_POST * 4 + r] = sc32[idx];
        const double* bd = &boxes_d[(size_t)idx * 4];
        double* dst = &bsel[(size_t)r * 4];
        dst[0] = bd[0]; dst[1] = bd[1]; dst[2] = bd[2]; dst[3] = bd[3];
        vsel[r] = (key >> 63) ? 1u : 0u;      // sign bit set <=> score >= 0 <=> valid
    }
}

// ---------------- NMS (fp64 IoU) ----------------
__global__ void rpn_nms_mask(const double* __restrict__ bsel, u64* __restrict__ mask) {
    int t = blockIdx.x * 256 + threadIdx.x;
    if (t >= N_PRE * NWORDS) return;
    int i = t / NWORDS, w = t - i * NWORDS;
    const double* bi = &bsel[(size_t)i * 4];
    double bix1 = bi[0], biy1 = bi[1], bix2 = bi[2], biy2 = bi[3];
    double ai = (bix2 - bix1 + 1.0) * (biy2 - biy1 + 1.0);
    u64 bits = 0ULL;
    int j0 = w * 64;
    for (int jj = 0; jj < 64; ++jj) {
        int j = j0 + jj;
        if (j >= N_PRE || j == i) continue;
        const double* bj = &bsel[(size_t)j * 4];
        double aj = (bj[2] - bj[0] + 1.0) * (bj[3] - bj[1] + 1.0);
        double xx1 = fmax(bix1, bj[0]), yy1 = fmax(biy1, bj[1]);
        double xx2 = fmin(bix2, bj[2]), yy2 = fmin(biy2, bj[3]);
        double iw = fmax(xx2 - xx1 + 1.0, 0.0), ih = fmax(yy2 - yy1 + 1.0, 0.0);
        double inter = iw * ih;
        double iou = inter / (ai + aj - inter);
        if (iou > 0.5) bits |= 1ULL << jj;
    }
    mask[(size_t)i * NWORDS + w] = bits;
}

__global__ __launch_bounds__(64) void rpn_nms_scan(
    const u64* __restrict__ mask, const unsigned* __restrict__ vsel,
    unsigned* __restrict__ keep, unsigned* __restrict__ rank) {
    int lane = threadIdx.x;
    u64 remv = 0ULL;
    int kc = 0;
    u64 pre[8];
    #pragma unroll
    for (int q = 0; q < 8; ++q)
        pre[q] = (lane < NWORDS) ? mask[(size_t)q * NWORDS + lane] : 0ULL;
    for (int i0 = 0; i0 < N_PRE; i0 += 8) {
        u64 nxt[8];
        #pragma unroll
        for (int q = 0; q < 8; ++q) {
            int r = i0 + 8 + q;
            nxt[q] = (r < N_PRE && lane < NWORDS) ? mask[(size_t)r * NWORDS + lane] : 0ULL;
        }
        #pragma unroll
        for (int q = 0; q < 8; ++q) {
            int i = i0 + q;
            int word = i >> 6, bit = i & 63;
            u64 rw = __shfl(remv, word);
            bool sup = (rw >> bit) & 1ULL;
            bool kp = (vsel[i] != 0u) && !sup;
            if (kp) remv |= pre[q];
            if (lane == 0) { keep[i] = kp ? 1u : 0u; rank[i] = (unsigned)kc; }
            kc += kp ? 1 : 0;
        }
        #pragma unroll
        for (int q = 0; q < 8; ++q) pre[q] = nxt[q];
    }
}

__global__ void rpn_finalize(const unsigned* __restrict__ keep, const unsigned* __restrict__ rank,
                             const double* __restrict__ bsel, float* __restrict__ out) {
    int i = blockIdx.x * 256 + threadIdx.x;
    if (i < N_PRE && keep[i] && rank[i] < N_POST) {
        const double* b = &bsel[(size_t)i * 4];
        float4 v = make_float4((float)b[0], (float)b[1], (float)b[2], (float)b[3]);
        ((float4*)out)[rank[i]] = v;
    }
}

// ---------------- launch ----------------
extern "C" void kernel_launch(void* const* d_in, const int* in_sizes, int n_in,
                              void* d_out, int out_size, void* d_ws, size_t ws_size,
                              hipStream_t stream) {
    const float* x   = (const float*)d_in[0];
    const float* wb  = (const float*)d_in[1];
    const float* bb  = (const float*)d_in[2];
    const float* wc  = (const float*)d_in[3];
    const float* bc  = (const float*)d_in[4];
    const float* wr  = (const float*)d_in[5];
    const float* br  = (const float*)d_in[6];
    float* out = (float*)d_out;

    char* ws = (char*)d_ws;
    // Total 35,224,320 bytes (well under the 57 MB proven-safe footprint).
    float*    wt      = (float*)(ws);                        //  0         18,874,368
    double*   logits  = (double*)(ws + 18874368);            //             7,340,032
    float*    wht     = (float*)(ws + 26214400);             //               114,688
    double*   boxes_d = (double*)(ws + 26329088);            //             4,718,592
    float*    sc32    = (float*)(ws + 31047680);             //               589,824
    unsigned* keys32  = (unsigned*)(ws + 31637504);          //               589,824
    u64*      ukey    = (u64*)(ws + 32227328);               //             1,179,648
    unsigned* hist1   = (unsigned*)(ws + 33406976);          //               262,144
    unsigned* hist2   = (unsigned*)(ws + 33669120);          //               262,144
    unsigned* meta    = (unsigned*)(ws + 33931264);          //                   256
    u64*      sel     = (u64*)(ws + 33931520);               //                32,768
    double*   bsel    = (double*)(ws + 33964288);            //                96,000
    unsigned* vsel    = (unsigned*)(ws + 34060288);          //                12,032
    u64*      mask    = (u64*)(ws + 34072320);               //             1,128,000
    unsigned* keep    = (unsigned*)(ws + 35200320);          //                12,000
    unsigned* rank    = (unsigned*)(ws + 35212320);          //                12,000

    hipMemsetAsync(logits, 0, 7340032, stream);
    hipMemsetAsync(hist1, 0, 262144 * 2 + 256, stream);      // hist1+hist2+meta (contiguous)
    hipMemsetAsync(d_out, 0, N_POST * 4 * sizeof(float), stream);

    rpn_prep_w   <<<18432, 256, 0, stream>>>(wb, wt);
    rpn_prep_wht <<<112,   256, 0, stream>>>(wc, wr, wht);
    rpn_conv_fused<<<dim3(128, 8), 256, 0, stream>>>(x, wt, bb, wht, logits);
    rpn_decode   <<<576, 256, 0, stream>>>(logits, bc, br, boxes_d, sc32, keys32, ukey);
    rpn_hist1    <<<576, 256, 0, stream>>>(keys32, hist1);
    rpn_select1  <<<1, 256, 0, stream>>>(hist1, meta);
    rpn_hist2    <<<576, 256, 0, stream>>>(keys32, meta, hist2);
    rpn_select2  <<<1, 256, 0, stream>>>(hist2, meta);
    rpn_compact  <<<576, 256, 0, stream>>>(keys32, meta, ukey, sel);
    rpn_sort     <<<1, 512, 0, stream>>>(sel, meta, boxes_d, sc32, out, bsel, vsel);
    rpn_nms_mask <<<(N_PRE * NWORDS + 255) / 256, 256, 0, stream>>>(bsel, mask);
    rpn_nms_scan <<<1, 64, 0, stream>>>(mask, vsel, keep, rank);
    rpn_finalize <<<12, 256, 0, stream>>>(keep, rank, bsel, out);
}